// Round 8
// baseline (342.618 us; speedup 1.0000x reference)
//
#include <hip/hip_runtime.h>
#include <hip/hip_fp16.h>

// out[M,N] = fp16( a[M,K] @ (w_q[K,N] * scale[K/G,N]) ), G=128, all dims 4096.
// Harness dtype contract: fp16 tensors passed/returned as FLOAT32.
// Round 8: reduce LDS-port traffic (the co-bottleneck: phase ~ 0.85*(LDS +
// MFMA) across R2..R7). B drops out of LDS entirely: bf fragments load
// DIRECTLY from Wt (L2) into registers - 4 wave-level dwordx4 per phase
// (16 rows x 64 contiguous B each), double-banked at distance 2. LDS traffic
// per CU per phase: 128 KB -> 80 KB (A reads 64 KB + A stage-writes 16 KB),
// below the 1242-cyc MFMA floor. n-major XCD swizzle keeps each XCD's B
// working set at 2 panels = 4 MB = L2-resident. A path unchanged from R2
// (ring-4 global_load_lds, source-side swizzle, counted vmcnt, never 0).
#define MDIM 4096
#define NDIM 4096
#define KDIM 4096
#define NT 256
#define WBLK 4096

typedef _Float16 f16x8 __attribute__((ext_vector_type(8)));
typedef float f32x4 __attribute__((ext_vector_type(4)));
typedef unsigned int u32;
typedef unsigned short u16;

__device__ inline __half2 as_half2(u32 u) { return __builtin_bit_cast(__half2, u); }
__device__ inline u32 as_u32(__half2 h) { return __builtin_bit_cast(u32, h); }
// __builtin_amdgcn_cvt_pkrtz returns __fp16 ext_vector(2); bit-cast directly.
__device__ inline u32 pkrtz(float a, float b) {
  return __builtin_bit_cast(u32, __builtin_amdgcn_cvt_pkrtz(a, b));
}

// async global -> LDS, 16 B/lane. LDS dst must be wave-uniform base + lane*16.
__device__ inline void load16_to_lds(const void* g, void* l) {
  __builtin_amdgcn_global_load_lds(
      (__attribute__((address_space(1))) const u32*)g,
      (__attribute__((address_space(3))) u32*)l,
      16, 0, 0);
}

template <int VM>
__device__ __forceinline__ void wait_vmcnt() {
  if constexpr (VM == 6)
    asm volatile("s_waitcnt vmcnt(6)" ::: "memory");
  else
    asm volatile("s_waitcnt vmcnt(0)" ::: "memory");
}

// ---- fused prepass: blocks [0,4096) dequant+transpose W, rest copy A ----
__global__ __launch_bounds__(NT) void prep(const float* __restrict__ A,
                                           _Float16* __restrict__ A16,
                                           const int* __restrict__ Wq,
                                           const float* __restrict__ Sc,
                                           _Float16* __restrict__ Wt) {
  // u32 staging [n][k-pair], stride 33 dwords: write bank (n+kp)%32 (2-way),
  // read bank (n+k2c+j)%32 (2-way). 8.25 KB -> high occupancy.
  __shared__ u32 Lt[64 * 33];
  const int tid = threadIdx.x;

  if (blockIdx.x >= WBLK) {
    // ---- A fp32 -> fp16 (exact: values are fp16-representable) ----
    const size_t b = blockIdx.x - WBLK;
    const size_t base = (b * NT + tid) * 8;
    const float4 f0 = *(const float4*)(A + base);
    const float4 f1 = *(const float4*)(A + base + 4);
    u32 pk[4];
    pk[0] = pkrtz(f0.x, f0.y);
    pk[1] = pkrtz(f0.z, f0.w);
    pk[2] = pkrtz(f1.x, f1.y);
    pk[3] = pkrtz(f1.z, f1.w);
    *(uint4*)(A16 + base) = *(const uint4*)pk;
    return;
  }

  // ---- W: dequant Wq [K][N] + transpose -> Wt f16 [N][K], 64x64 tile ----
  const int n0 = (blockIdx.x & 63) * 64;
  const int k0 = (blockIdx.x >> 6) * 64;
  const int g = k0 >> 7;  // 64-tile lies within one 128-group

  // phase 1: coalesced read of two adjacent k-rows, dequant to packed k-pair
#pragma unroll
  for (int r = 0; r < 2; ++r) {
    const int idx = r * 256 + tid;
    const int kp = idx >> 4;          // k-pair index 0..31
    const int col4 = (idx & 15) * 4;  // n within tile, 4 at a time
    const int4 va = *(const int4*)(Wq + (size_t)(k0 + 2 * kp) * NDIM + n0 + col4);
    const int4 vb = *(const int4*)(Wq + (size_t)(k0 + 2 * kp + 1) * NDIM + n0 + col4);
    const float4 s = *(const float4*)(Sc + (size_t)g * NDIM + n0 + col4);
    const float sf[4] = {s.x, s.y, s.z, s.w};
    const int av[4] = {va.x, va.y, va.z, va.w};
    const int bv[4] = {vb.x, vb.y, vb.z, vb.w};
#pragma unroll
    for (int i = 0; i < 4; ++i) {
      // fp16 bits of (1024+v): 0x6400|v; hfma gives single-rounded v*s.
      const __half hs = __float2half(sf[i]);
      const __half2 s2 = __half2half2(hs);
      const __half2 nb = __half2half2(__hmul(hs, __float2half(-1024.0f)));
      const u32 u = (u32)av[i] | ((u32)bv[i] << 16) | 0x64006400u;
      // u32 holds (w[2kp]*s, w[2kp+1]*s) = the contiguous k-pair for Wt[n].
      Lt[(size_t)(col4 + i) * 33 + kp] = as_u32(__hfma2(as_half2(u), s2, nb));
    }
  }
  __syncthreads();

  // phase 2: gather 4 k-pair dwords per thread, coalesced 16B writes to Wt
#pragma unroll
  for (int r = 0; r < 2; ++r) {
    const int idx = r * 256 + tid;
    const int n = idx >> 3;          // 0..63
    const int k2c = (idx & 7) * 4;   // dword column 0..28 (= k/2)
    u32 v[4];
#pragma unroll
    for (int j = 0; j < 4; ++j) v[j] = Lt[(size_t)n * 33 + k2c + j];
    *(uint4*)(Wt + (size_t)(n0 + n) * KDIM + k0 + k2c * 2) = *(const uint4*)v;
  }
}

// -------- 256x256 GEMM: A via LDS ring-4, B direct global->register -------
// A: LDS ring of 4 slots [256][32] f16 (16 KB each, 64 KB total). Phase p
//    reads slot p&3; stages piece p+2 into slot (p+2)&3 via global_load_lds
//    (source-side swizzle: phys chunk = logical ^ ((row>>1)&3)).
// B: bf fragment (4x f16x8 per wave) loaded straight from Wt each phase,
//    double-banked (bfA even / bfB odd phases), loaded at distance 2.
//    Wave access = 16 rows x 64 contiguous B -> 16 cachelines, L2-resident.
// vmcnt: per body 6 events (2 A-gload_lds + 4 B-reg loads). Top-of-phase
//    wait vmcnt(6) = previous body outstanding; drains body p-2 -> A(p) in
//    LDS and B(p) in regs. Never 0 in the loop.
__global__ __launch_bounds__(512) void gemm_f16(const _Float16* __restrict__ A16,
                                                const _Float16* __restrict__ Wt,
                                                float* __restrict__ C) {
  __shared__ __align__(16) _Float16 As[4 * 256 * 32];  // 64 KB

  const int tid = threadIdx.x;
  // n-major XCD swizzle (bijective, 256 = 8 XCD x 32): XCD x owns n-blocks
  // {2x, 2x+1} -> per-XCD B working set = 2 panels x 2 MB = 4 MB = L2 size.
  const int g = blockIdx.x;
  const int xcd = g & 7;
  const int i5 = g >> 3;           // 0..31
  const int bx = xcd * 2 + (i5 & 1);  // n-block
  const int by = i5 >> 1;             // m-block
  const int m_base = by * 256;
  const int n_base = bx * 256;

  const int wave = tid >> 6;
  const int lane = tid & 63;
  const int l15 = lane & 15;
  const int quad = lane >> 4;
  const int mq = wave >> 2;  // 0..1 : 128-row band
  const int nq = wave & 3;   // 0..3 : 64-col band
  const int gq = (l15 >> 1) & 3;       // row-swizzle term (row ≡ l15 mod 16)
  const int pchunk = quad ^ gq;        // physical 16B chunk for A frag reads

  f32x4 acc[8][4];
#pragma unroll
  for (int i = 0; i < 8; ++i)
#pragma unroll
    for (int j = 0; j < 4; ++j) acc[i][j] = (f32x4)0.0f;

  // B fragment base for this thread: row = n_base + nq*64 + j*16 + l15.
  const _Float16* const wt_base =
      Wt + (size_t)(n_base + nq * 64 + l15) * KDIM + quad * 8;

  // load B fragments for k-half piece q into a register bank (4 vmcnt events)
  auto loadB = [&](int q, f16x8(&bf)[4]) {
    const _Float16* src = wt_base + (size_t)q * 32;
#pragma unroll
    for (int j = 0; j < 4; ++j)
      bf[j] = *(const f16x8*)(src + (size_t)(j * 16) * KDIM);
  };

  // stage A k-half piece q into slot q&3: 2 global_load_lds per thread.
  auto stageA = [&](int q) {
    const size_t kof = (size_t)q * 32;
    const int s = q & 3;
#pragma unroll
    for (int L = 0; L < 2; ++L) {
      const int cc = L * 512 + tid;        // 0..1023 : (row, phys chunk)
      const int row = cc >> 2;
      const int lch = (cc & 3) ^ ((row >> 1) & 3);  // logical chunk at phys
      load16_to_lds(A16 + (size_t)(m_base + row) * KDIM + kof + lch * 8,
                    (char*)As + (size_t)s * 16384 + (size_t)cc * 16);
    }
  };

  // caller performs the top-of-phase wait_vmcnt BEFORE calling.
  // body: barrier; 8 af ds_reads; stageA(p+2); lgkm0; 32 MFMA (bf bank);
  //        loadB(p+2) into the same bank (after its last use this phase).
  auto phase_body = [&](int p, f16x8(&bf)[4], bool dostage) {
    __builtin_amdgcn_s_barrier();
    asm volatile("" ::: "memory");  // no LDS access hoists above the barrier
    const int s = p & 3;
    const _Float16* Ab = (const _Float16*)((const char*)As + (size_t)s * 16384);
    f16x8 af[8];
#pragma unroll
    for (int i = 0; i < 8; ++i) {
      const int row = mq * 128 + i * 16 + l15;
      af[i] = *(const f16x8*)(Ab + (size_t)row * 32 + pchunk * 8);
    }
    if (dostage) stageA(p + 2);
    asm volatile("s_waitcnt lgkmcnt(0)" ::: "memory");
    __builtin_amdgcn_sched_barrier(0);  // keep MFMAs below the wait (rule 18)
    __builtin_amdgcn_s_setprio(1);
#pragma unroll
    for (int i = 0; i < 8; ++i)
#pragma unroll
      for (int j = 0; j < 4; ++j)
        acc[i][j] = __builtin_amdgcn_mfma_f32_16x16x32_f16(af[i], bf[j],
                                                           acc[i][j], 0, 0, 0);
    __builtin_amdgcn_s_setprio(0);
    if (dostage) loadB(p + 2, bf);  // refill same-parity bank (distance 2)
  };

  f16x8 bfA[4], bfB[4];

  // prologue: bodies "-2","-1": pieces 0,1 in flight (12 vmcnt events)
  stageA(0);
  loadB(0, bfA);
  stageA(1);
  loadB(1, bfB);

  // 128 phases = 64 K-tiles x 2 k-halves, unrolled in parity pairs.
  // Top-of-phase vmcnt(6): previous body's 6 events outstanding; body p-2
  // drained -> A(p) in LDS, B(p) in bank. Tail: 126 -> 6, 127 -> 0.
  for (int p = 0; p < 126; p += 2) {
    wait_vmcnt<6>();
    phase_body(p, bfA, true);
    wait_vmcnt<6>();
    phase_body(p + 1, bfB, true);
  }
  wait_vmcnt<6>();
  phase_body(126, bfA, false);
  wait_vmcnt<0>();
  phase_body(127, bfB, false);

  // epilogue: C/D layout col=lane&15, row=quad*4+reg; fp16-round, store f32
#pragma unroll
  for (int i = 0; i < 8; ++i) {
#pragma unroll
    for (int j = 0; j < 4; ++j) {
      const int col = n_base + nq * 64 + j * 16 + l15;
#pragma unroll
      for (int r = 0; r < 4; ++r) {
        const int row = m_base + mq * 128 + i * 16 + quad * 4 + r;
        C[(size_t)row * NDIM + col] = __half2float(__float2half(acc[i][j][r]));
      }
    }
  }
}

// ---------------- fallback: fused single-kernel (round-3, 331 us) --------
#define STR 72
__global__ __launch_bounds__(NT) void qgemm_fused(
    const float* __restrict__ A, const int* __restrict__ Wq,
    const float* __restrict__ Sc, float* __restrict__ C) {
  __shared__ __align__(16) _Float16 As[128 * STR];
  __shared__ __align__(16) _Float16 Bs[128 * STR];
  const int tid = threadIdx.x;
  const int bx = blockIdx.x & 31, by = blockIdx.x >> 5;
  const int m_base = by * 128, n_base = bx * 128;
  const int wave = tid >> 6, lane = tid & 63;
  const int l15 = lane & 15, quad = lane >> 4;
  const int wm = (wave & 1) * 64, wn = (wave >> 1) * 64;
  const int bn_local = tid & 127, bk_half = (tid >> 7) * 8;
  const int gn = n_base + bn_local;
  f32x4 acc[4][4];
#pragma unroll
  for (int i = 0; i < 4; ++i)
#pragma unroll
    for (int j = 0; j < 4; ++j) acc[i][j] = (f32x4)0.0f;
  for (int kt = 0; kt < KDIM / 64; ++kt) {
    const int k0 = kt * 64;
    __syncthreads();
#pragma unroll
    for (int i = 0; i < 8; ++i) {
      const int c = i * 256 + tid;
      const int row = c >> 4, col4 = (c & 15) * 4;
      const float4 f = *(const float4*)(A + (size_t)(m_base + row) * KDIM + k0 + col4);
      u32 pk[2];
      pk[0] = pkrtz(f.x, f.y);
      pk[1] = pkrtz(f.z, f.w);
      *(uint2*)&As[(size_t)row * STR + col4] = *(const uint2*)pk;
    }
    {
      const __half hs = __float2half(Sc[(size_t)(k0 >> 7) * NDIM + gn]);
      const __half2 s2 = __half2half2(hs);
      const __half2 nb2 = __half2half2(__hmul(hs, __float2half(-1024.0f)));
#pragma unroll
      for (int it = 0; it < 4; ++it) {
        const int k = bk_half + it * 16;
        u32 v[8];
#pragma unroll
        for (int j = 0; j < 8; ++j)
          v[j] = (u32)Wq[(size_t)(k0 + k + j) * NDIM + gn];
        u32 pk[4];
#pragma unroll
        for (int p = 0; p < 4; ++p) {
          u32 u = v[2 * p] | (v[2 * p + 1] << 16) | 0x64006400u;
          pk[p] = as_u32(__hfma2(as_half2(u), s2, nb2));
        }
        *(uint4*)&Bs[(size_t)bn_local * STR + k] = *(const uint4*)pk;
      }
    }
    __syncthreads();
#pragma unroll
    for (int ks = 0; ks < 64; ks += 32) {
      f16x8 af[4], bf[4];
#pragma unroll
      for (int i = 0; i < 4; ++i)
        af[i] = *(const f16x8*)&As[(size_t)(wm + i * 16 + l15) * STR + ks + quad * 8];
#pragma unroll
      for (int j = 0; j < 4; ++j)
        bf[j] = *(const f16x8*)&Bs[(size_t)(wn + j * 16 + l15) * STR + ks + quad * 8];
#pragma unroll
      for (int i = 0; i < 4; ++i)
#pragma unroll
        for (int j = 0; j < 4; ++j)
          acc[i][j] = __builtin_amdgcn_mfma_f32_16x16x32_f16(af[i], bf[j],
                                                             acc[i][j], 0, 0, 0);
    }
  }
#pragma unroll
  for (int i = 0; i < 4; ++i)
#pragma unroll
    for (int j = 0; j < 4; ++j) {
      const int col = n_base + wn + j * 16 + l15;
#pragma unroll
      for (int r = 0; r < 4; ++r) {
        const int row = m_base + wm + i * 16 + quad * 4 + r;
        C[(size_t)row * NDIM + col] = __half2float(__float2half(acc[i][j][r]));
      }
    }
}

extern "C" void kernel_launch(void* const* d_in, const int* in_sizes, int n_in,
                              void* d_out, int out_size, void* d_ws, size_t ws_size,
                              hipStream_t stream) {
  const float* a = (const float*)d_in[0];
  const int* wq = (const int*)d_in[1];
  const float* sc = (const float*)d_in[2];
  float* out = (float*)d_out;

  const size_t a16_bytes = (size_t)MDIM * KDIM * 2;  // 32 MiB
  const size_t wt_bytes = (size_t)NDIM * KDIM * 2;   // 32 MiB

  if (ws_size >= a16_bytes + wt_bytes) {
    _Float16* a16 = (_Float16*)d_ws;
    _Float16* wt = (_Float16*)((char*)d_ws + a16_bytes);
    const int a_blocks = (MDIM * KDIM) / (NT * 8);  // 8192
    prep<<<WBLK + a_blocks, NT, 0, stream>>>(a, a16, wq, sc, wt);
    gemm_f16<<<(MDIM / 256) * (NDIM / 256), 512, 0, stream>>>(a16, wt, out);
  } else {
    qgemm_fused<<<(MDIM / 128) * (NDIM / 128), NT, 0, stream>>>(a, wq, sc, out);
  }
}

// Round 9
// 321.748 us; speedup vs baseline: 1.0649x; 1.0649x over previous
//
#include <hip/hip_runtime.h>
#include <hip/hip_fp16.h>

// out[M,N] = fp16( a[M,K] @ (w_q[K,N] * scale[K/G,N]) ), G=128, all dims 4096.
// Harness dtype contract: fp16 tensors passed/returned as FLOAT32.
// Round 9: single persistent kernel. R2's gemm (122.9 us, best of 7 variants)
// is kept VERBATIM; prep (A f32->f16 copy + W dequant/transpose) is fused in
// front of it, separated by a device-wide soft barrier (ticket atomicAdd +
// spin, release/acquire __threadfence for cross-XCD visibility). Geometry
// already guarantees co-residency: 256 blocks x 512 thr x ~137 KB LDS = 1
// block/CU on 256 CUs. Counter zeroed per replay via hipMemsetAsync node.
// Rationale: total - gemm ~ 155-165 us across ALL rounds; ~110 of it is
// fixed per-iteration overhead, and 2 dependent dispatches -> 1 is the only
// structural lever left on it.
#define MDIM 4096
#define NDIM 4096
#define KDIM 4096
#define NT 256

typedef _Float16 f16x8 __attribute__((ext_vector_type(8)));
typedef float f32x4 __attribute__((ext_vector_type(4)));
typedef unsigned int u32;
typedef unsigned short u16;

__device__ inline __half2 as_half2(u32 u) { return __builtin_bit_cast(__half2, u); }
__device__ inline u32 as_u32(__half2 h) { return __builtin_bit_cast(u32, h); }
// __builtin_amdgcn_cvt_pkrtz returns __fp16 ext_vector(2); bit-cast directly.
__device__ inline u32 pkrtz(float a, float b) {
  return __builtin_bit_cast(u32, __builtin_amdgcn_cvt_pkrtz(a, b));
}

// async global -> LDS, 16 B/lane. LDS dst must be wave-uniform base + lane*16.
__device__ inline void load16_to_lds(const void* g, void* l) {
  __builtin_amdgcn_global_load_lds(
      (__attribute__((address_space(1))) const u32*)g,
      (__attribute__((address_space(3))) u32*)l,
      16, 0, 0);
}

template <int VM>
__device__ __forceinline__ void wait_vmcnt() {
  if constexpr (VM == 8)
    asm volatile("s_waitcnt vmcnt(8)" ::: "memory");
  else if constexpr (VM == 4)
    asm volatile("s_waitcnt vmcnt(4)" ::: "memory");
  else
    asm volatile("s_waitcnt vmcnt(0)" ::: "memory");
}

// ------------- fused persistent kernel: prep + barrier + gemm -------------
__global__ __launch_bounds__(512) void fused_all(const float* __restrict__ A,
                                                 const int* __restrict__ Wq,
                                                 const float* __restrict__ Sc,
                                                 float* __restrict__ C,
                                                 _Float16* __restrict__ A16,
                                                 _Float16* __restrict__ Wt,
                                                 u32* __restrict__ cnt) {
  __shared__ __align__(16) _Float16 As[4 * 256 * 32];  // 64 KB (gemm ring)
  __shared__ __align__(16) _Float16 Bs[4 * 256 * 32];  // 64 KB (gemm ring)
  __shared__ u32 Lt[64 * 33];                          // 8.25 KB (transpose)

  const int tid = threadIdx.x;
  const int b = blockIdx.x;  // 0..255

  // ================= prep part 1: W dequant+transpose, 16 tiles ==========
  // tile w: n0 = (w&63)*64, k0 = (w>>6)*64. u32 staging [n][33]: write bank
  // (n+kp)%32 (2-way free), read bank (n+k2c+j)%32 (2-way free).
  for (int i = 0; i < 16; ++i) {
    const int w = b * 16 + i;
    const int n0 = (w & 63) * 64;
    const int k0 = (w >> 6) * 64;
    const int g = k0 >> 7;  // 64-tile lies within one 128-group

    {  // phase 1: coalesced read of two adjacent k-rows -> packed k-pair
      const int kp = tid >> 4;          // k-pair index 0..31
      const int col4 = (tid & 15) * 4;  // n within tile, 4 at a time
      const int4 va = *(const int4*)(Wq + (size_t)(k0 + 2 * kp) * NDIM + n0 + col4);
      const int4 vb = *(const int4*)(Wq + (size_t)(k0 + 2 * kp + 1) * NDIM + n0 + col4);
      const float4 s = *(const float4*)(Sc + (size_t)g * NDIM + n0 + col4);
      const float sf[4] = {s.x, s.y, s.z, s.w};
      const int av[4] = {va.x, va.y, va.z, va.w};
      const int bv[4] = {vb.x, vb.y, vb.z, vb.w};
#pragma unroll
      for (int q = 0; q < 4; ++q) {
        // fp16 bits of (1024+v): 0x6400|v; hfma gives single-rounded v*s.
        const __half hs = __float2half(sf[q]);
        const __half2 s2 = __half2half2(hs);
        const __half2 nb = __half2half2(__hmul(hs, __float2half(-1024.0f)));
        const u32 u = (u32)av[q] | ((u32)bv[q] << 16) | 0x64006400u;
        Lt[(size_t)(col4 + q) * 33 + kp] = as_u32(__hfma2(as_half2(u), s2, nb));
      }
    }
    __syncthreads();
    {  // phase 2: gather 4 k-pair dwords, coalesced 16B writes to Wt [n][k]
      const int n = tid >> 3;          // 0..63
      const int k2c = (tid & 7) * 4;   // dword column (= k/2)
      u32 v[4];
#pragma unroll
      for (int j = 0; j < 4; ++j) v[j] = Lt[(size_t)n * 33 + k2c + j];
      *(uint4*)(Wt + (size_t)(n0 + n) * KDIM + k0 + k2c * 2) = *(const uint4*)v;
    }
    __syncthreads();  // Lt reused next tile
  }

  // ================= prep part 2: A fp32 -> fp16 copy ====================
#pragma unroll
  for (int it = 0; it < 16; ++it) {
    const size_t idx = (size_t)it * 131072 + (size_t)b * 512 + tid;
    const size_t base = idx * 8;
    const float4 f0 = *(const float4*)(A + base);
    const float4 f1 = *(const float4*)(A + base + 4);
    u32 pk[4];
    pk[0] = pkrtz(f0.x, f0.y);
    pk[1] = pkrtz(f0.z, f0.w);
    pk[2] = pkrtz(f1.x, f1.y);
    pk[3] = pkrtz(f1.z, f1.w);
    *(uint4*)(A16 + base) = *(const uint4*)pk;
  }

  // ================= device-wide soft barrier ============================
  // cnt is memset to 0 before this kernel each replay. All 256 blocks are
  // co-resident (1 block/CU by LDS). Release fence publishes prep writes
  // (agent-scope wbl2: cross-XCD per guide G16); acquire fence invalidates.
  __syncthreads();
  if (tid == 0) {
    __threadfence();           // release: publish A16/Wt device-wide
    atomicAdd(cnt, 1u);
    while (atomicAdd(cnt, 0u) < 256u) __builtin_amdgcn_s_sleep(2);
    __threadfence();           // acquire: no stale A16/Wt from local L2
  }
  __syncthreads();

  // ================= gemm: R2-verified body, verbatim ====================
  const int bx = b & 15;  // n-block
  const int by = b >> 4;  // m-block
  const int m_base = by * 256;
  const int n_base = bx * 256;

  const int wave = tid >> 6;
  const int lane = tid & 63;
  const int l15 = lane & 15;
  const int quad = lane >> 4;
  const int mq = wave >> 2;  // 0..1 : 128-row band
  const int nq = wave & 3;   // 0..3 : 64-col band
  const int gq = (l15 >> 1) & 3;       // row-swizzle term (row ≡ l15 mod 16)
  const int pchunk = quad ^ gq;        // physical 16B chunk for frag reads

  f32x4 acc[8][4];
#pragma unroll
  for (int i = 0; i < 8; ++i)
#pragma unroll
    for (int j = 0; j < 4; ++j) acc[i][j] = (f32x4)0.0f;

  // stage pieces (A khalf + B khalf) for phase p into slot p&3.
  auto stage = [&](int p) {
    const int T = p >> 1;        // K-tile
    const int h = p & 1;         // k-half within tile
    const int s = p & 3;         // slot
    const size_t kof = (size_t)T * 64 + (size_t)h * 32;
#pragma unroll
    for (int L = 0; L < 2; ++L) {
      const int cc = L * 512 + tid;        // 0..1023 : (row, phys chunk)
      const int row = cc >> 2;
      const int lch = (cc & 3) ^ ((row >> 1) & 3);  // logical chunk at phys
      load16_to_lds(A16 + (size_t)(m_base + row) * KDIM + kof + lch * 8,
                    (char*)As + (size_t)s * 16384 + (size_t)cc * 16);
    }
#pragma unroll
    for (int L = 0; L < 2; ++L) {
      const int cc = L * 512 + tid;
      const int row = cc >> 2;
      const int lch = (cc & 3) ^ ((row >> 1) & 3);
      load16_to_lds(Wt + (size_t)(n_base + row) * KDIM + kof + lch * 8,
                    (char*)Bs + (size_t)s * 16384 + (size_t)cc * 16);
    }
  };

  auto phase_body = [&](int p, bool dostage) {
    __builtin_amdgcn_s_barrier();
    asm volatile("" ::: "memory");  // no LDS access hoists above the barrier
    const int s = p & 3;
    const _Float16* Ab = (const _Float16*)((const char*)As + (size_t)s * 16384);
    const _Float16* Bb = (const _Float16*)((const char*)Bs + (size_t)s * 16384);
    f16x8 af[8], bf[4];
#pragma unroll
    for (int i = 0; i < 8; ++i) {
      const int row = mq * 128 + i * 16 + l15;
      af[i] = *(const f16x8*)(Ab + (size_t)row * 32 + pchunk * 8);
    }
#pragma unroll
    for (int j = 0; j < 4; ++j) {
      const int row = nq * 64 + j * 16 + l15;
      bf[j] = *(const f16x8*)(Bb + (size_t)row * 32 + pchunk * 8);
    }
    if (dostage) stage(p + 3);
    asm volatile("s_waitcnt lgkmcnt(0)" ::: "memory");
    __builtin_amdgcn_sched_barrier(0);  // keep MFMAs below the wait (rule 18)
    __builtin_amdgcn_s_setprio(1);
#pragma unroll
    for (int i = 0; i < 8; ++i)
#pragma unroll
      for (int j = 0; j < 4; ++j)
        acc[i][j] = __builtin_amdgcn_mfma_f32_16x16x32_f16(af[i], bf[j],
                                                           acc[i][j], 0, 0, 0);
    __builtin_amdgcn_s_setprio(0);
  };

  // prologue: pieces for phases 0,1,2 (12 vmcnt events in flight)
  stage(0);
  stage(1);
  stage(2);

  // 128 phases = 64 K-tiles x 2 k-halves. vmcnt(8): phases p-1,p-2 in
  // flight, phase p's pieces (staged at p-3) guaranteed landed before the
  // entry barrier (all waves execute the wait pre-barrier).
  for (int p = 0; p < 125; ++p) {
    wait_vmcnt<8>();
    phase_body(p, true);
  }
  wait_vmcnt<8>();
  phase_body(125, false);
  wait_vmcnt<4>();
  phase_body(126, false);
  wait_vmcnt<0>();
  phase_body(127, false);

  // epilogue: C/D layout col=lane&15, row=quad*4+reg; fp16-round, store f32
#pragma unroll
  for (int i = 0; i < 8; ++i) {
#pragma unroll
    for (int j = 0; j < 4; ++j) {
      const int col = n_base + nq * 64 + j * 16 + l15;
#pragma unroll
      for (int r = 0; r < 4; ++r) {
        const int row = m_base + mq * 128 + i * 16 + quad * 4 + r;
        C[(size_t)row * NDIM + col] = __half2float(__float2half(acc[i][j][r]));
      }
    }
  }
}

// ---------------- fallback: fused single-kernel (round-3, 331 us) --------
#define STR 72
__global__ __launch_bounds__(NT) void qgemm_fused(
    const float* __restrict__ A, const int* __restrict__ Wq,
    const float* __restrict__ Sc, float* __restrict__ C) {
  __shared__ __align__(16) _Float16 As[128 * STR];
  __shared__ __align__(16) _Float16 Bs[128 * STR];
  const int tid = threadIdx.x;
  const int bx = blockIdx.x & 31, by = blockIdx.x >> 5;
  const int m_base = by * 128, n_base = bx * 128;
  const int wave = tid >> 6, lane = tid & 63;
  const int l15 = lane & 15, quad = lane >> 4;
  const int wm = (wave & 1) * 64, wn = (wave >> 1) * 64;
  const int bn_local = tid & 127, bk_half = (tid >> 7) * 8;
  const int gn = n_base + bn_local;
  f32x4 acc[4][4];
#pragma unroll
  for (int i = 0; i < 4; ++i)
#pragma unroll
    for (int j = 0; j < 4; ++j) acc[i][j] = (f32x4)0.0f;
  for (int kt = 0; kt < KDIM / 64; ++kt) {
    const int k0 = kt * 64;
    __syncthreads();
#pragma unroll
    for (int i = 0; i < 8; ++i) {
      const int c = i * 256 + tid;
      const int row = c >> 4, col4 = (c & 15) * 4;
      const float4 f = *(const float4*)(A + (size_t)(m_base + row) * KDIM + k0 + col4);
      u32 pk[2];
      pk[0] = pkrtz(f.x, f.y);
      pk[1] = pkrtz(f.z, f.w);
      *(uint2*)&As[(size_t)row * STR + col4] = *(const uint2*)pk;
    }
    {
      const __half hs = __float2half(Sc[(size_t)(k0 >> 7) * NDIM + gn]);
      const __half2 s2 = __half2half2(hs);
      const __half2 nb2 = __half2half2(__hmul(hs, __float2half(-1024.0f)));
#pragma unroll
      for (int it = 0; it < 4; ++it) {
        const int k = bk_half + it * 16;
        u32 v[8];
#pragma unroll
        for (int j = 0; j < 8; ++j)
          v[j] = (u32)Wq[(size_t)(k0 + k + j) * NDIM + gn];
        u32 pk[4];
#pragma unroll
        for (int p = 0; p < 4; ++p) {
          u32 u = v[2 * p] | (v[2 * p + 1] << 16) | 0x64006400u;
          pk[p] = as_u32(__hfma2(as_half2(u), s2, nb2));
        }
        *(uint4*)&Bs[(size_t)bn_local * STR + k] = *(const uint4*)pk;
      }
    }
    __syncthreads();
#pragma unroll
    for (int ks = 0; ks < 64; ks += 32) {
      f16x8 af[4], bf[4];
#pragma unroll
      for (int i = 0; i < 4; ++i)
        af[i] = *(const f16x8*)&As[(size_t)(wm + i * 16 + l15) * STR + ks + quad * 8];
#pragma unroll
      for (int j = 0; j < 4; ++j)
        bf[j] = *(const f16x8*)&Bs[(size_t)(wn + j * 16 + l15) * STR + ks + quad * 8];
#pragma unroll
      for (int i = 0; i < 4; ++i)
#pragma unroll
        for (int j = 0; j < 4; ++j)
          acc[i][j] = __builtin_amdgcn_mfma_f32_16x16x32_f16(af[i], bf[j],
                                                             acc[i][j], 0, 0, 0);
    }
  }
#pragma unroll
  for (int i = 0; i < 4; ++i)
#pragma unroll
    for (int j = 0; j < 4; ++j) {
      const int col = n_base + wn + j * 16 + l15;
#pragma unroll
      for (int r = 0; r < 4; ++r) {
        const int row = m_base + wm + i * 16 + quad * 4 + r;
        C[(size_t)row * NDIM + col] = __half2float(__float2half(acc[i][j][r]));
      }
    }
}

extern "C" void kernel_launch(void* const* d_in, const int* in_sizes, int n_in,
                              void* d_out, int out_size, void* d_ws, size_t ws_size,
                              hipStream_t stream) {
  const float* a = (const float*)d_in[0];
  const int* wq = (const int*)d_in[1];
  const float* sc = (const float*)d_in[2];
  float* out = (float*)d_out;

  const size_t a16_bytes = (size_t)MDIM * KDIM * 2;  // 32 MiB
  const size_t wt_bytes = (size_t)NDIM * KDIM * 2;   // 32 MiB

  if (ws_size >= a16_bytes + wt_bytes + 4096) {
    _Float16* a16 = (_Float16*)d_ws;
    _Float16* wt = (_Float16*)((char*)d_ws + a16_bytes);
    u32* cnt = (u32*)((char*)d_ws + a16_bytes + wt_bytes);
    hipMemsetAsync(cnt, 0, 4, stream);
    fused_all<<<256, 512, 0, stream>>>(a, wq, sc, out, a16, wt, cnt);
  } else {
    qgemm_fused<<<(MDIM / 128) * (NDIM / 128), NT, 0, stream>>>(a, wq, sc, out);
  }
}

// Round 10
// 293.701 us; speedup vs baseline: 1.1666x; 1.0955x over previous
//
#include <hip/hip_runtime.h>
#include <hip/hip_fp16.h>

// out[M,N] = fp16( a[M,K] @ (w_q[K,N] * scale[K/G,N]) ), G=128, all dims 4096.
// Harness dtype contract: fp16 tensors passed/returned as FLOAT32.
// Round 10: revert round-9 fusion (110 us residual is harness-fixed; fusion
// only added barrier skew). Back to R4's two-dispatch structure with ONE
// geometry change in gemm: 4 waves x 128x128-per-wave (was 8 x 128x64).
// Serial model (validated R2-R8): phase = LDS-read + MFMA cycles. Fatter
// wave tile halves LDS reads per MFMA: 768+1242 vs 1152+1242 cyc -> ~12%
// faster gemm. Costs acc 256 VGPR -> 1 wave/SIMD, acceptable because the
// structure is barrier-lockstep (TLP was unused). Prep identical to R4.
#define MDIM 4096
#define NDIM 4096
#define KDIM 4096
#define NT 256
#define WBLK 4096

typedef _Float16 f16x8 __attribute__((ext_vector_type(8)));
typedef float f32x4 __attribute__((ext_vector_type(4)));
typedef unsigned int u32;
typedef unsigned short u16;

__device__ inline __half2 as_half2(u32 u) { return __builtin_bit_cast(__half2, u); }
__device__ inline u32 as_u32(__half2 h) { return __builtin_bit_cast(u32, h); }
// __builtin_amdgcn_cvt_pkrtz returns __fp16 ext_vector(2); bit-cast directly.
__device__ inline u32 pkrtz(float a, float b) {
  return __builtin_bit_cast(u32, __builtin_amdgcn_cvt_pkrtz(a, b));
}

// async global -> LDS, 16 B/lane. LDS dst must be wave-uniform base + lane*16.
__device__ inline void load16_to_lds(const void* g, void* l) {
  __builtin_amdgcn_global_load_lds(
      (__attribute__((address_space(1))) const u32*)g,
      (__attribute__((address_space(3))) u32*)l,
      16, 0, 0);
}

template <int VM>
__device__ __forceinline__ void wait_vmcnt() {
  if constexpr (VM == 16)
    asm volatile("s_waitcnt vmcnt(16)" ::: "memory");
  else if constexpr (VM == 8)
    asm volatile("s_waitcnt vmcnt(8)" ::: "memory");
  else
    asm volatile("s_waitcnt vmcnt(0)" ::: "memory");
}

// ---- fused prepass: blocks [0,4096) dequant+transpose W, rest copy A ----
__global__ __launch_bounds__(NT) void prep(const float* __restrict__ A,
                                           _Float16* __restrict__ A16,
                                           const int* __restrict__ Wq,
                                           const float* __restrict__ Sc,
                                           _Float16* __restrict__ Wt) {
  // u32 staging [n][k-pair], stride 33 dwords: write bank (n+kp)%32 (2-way),
  // read bank (n+k2c+j)%32 (2-way). 8.25 KB -> high occupancy.
  __shared__ u32 Lt[64 * 33];
  const int tid = threadIdx.x;

  if (blockIdx.x >= WBLK) {
    // ---- A fp32 -> fp16 (exact: values are fp16-representable) ----
    const size_t b = blockIdx.x - WBLK;
    const size_t base = (b * NT + tid) * 8;
    const float4 f0 = *(const float4*)(A + base);
    const float4 f1 = *(const float4*)(A + base + 4);
    u32 pk[4];
    pk[0] = pkrtz(f0.x, f0.y);
    pk[1] = pkrtz(f0.z, f0.w);
    pk[2] = pkrtz(f1.x, f1.y);
    pk[3] = pkrtz(f1.z, f1.w);
    *(uint4*)(A16 + base) = *(const uint4*)pk;
    return;
  }

  // ---- W: dequant Wq [K][N] + transpose -> Wt f16 [N][K], 64x64 tile ----
  const int n0 = (blockIdx.x & 63) * 64;
  const int k0 = (blockIdx.x >> 6) * 64;
  const int g = k0 >> 7;  // 64-tile lies within one 128-group

  // phase 1: coalesced read of two adjacent k-rows, dequant to packed k-pair
#pragma unroll
  for (int r = 0; r < 2; ++r) {
    const int idx = r * 256 + tid;
    const int kp = idx >> 4;          // k-pair index 0..31
    const int col4 = (idx & 15) * 4;  // n within tile, 4 at a time
    const int4 va = *(const int4*)(Wq + (size_t)(k0 + 2 * kp) * NDIM + n0 + col4);
    const int4 vb = *(const int4*)(Wq + (size_t)(k0 + 2 * kp + 1) * NDIM + n0 + col4);
    const float4 s = *(const float4*)(Sc + (size_t)g * NDIM + n0 + col4);
    const float sf[4] = {s.x, s.y, s.z, s.w};
    const int av[4] = {va.x, va.y, va.z, va.w};
    const int bv[4] = {vb.x, vb.y, vb.z, vb.w};
#pragma unroll
    for (int i = 0; i < 4; ++i) {
      // fp16 bits of (1024+v): 0x6400|v; hfma gives single-rounded v*s.
      const __half hs = __float2half(sf[i]);
      const __half2 s2 = __half2half2(hs);
      const __half2 nb = __half2half2(__hmul(hs, __float2half(-1024.0f)));
      const u32 u = (u32)av[i] | ((u32)bv[i] << 16) | 0x64006400u;
      // u32 holds (w[2kp]*s, w[2kp+1]*s) = the contiguous k-pair for Wt[n].
      Lt[(size_t)(col4 + i) * 33 + kp] = as_u32(__hfma2(as_half2(u), s2, nb));
    }
  }
  __syncthreads();

  // phase 2: gather 4 k-pair dwords per thread, coalesced 16B writes to Wt
#pragma unroll
  for (int r = 0; r < 2; ++r) {
    const int idx = r * 256 + tid;
    const int n = idx >> 3;          // 0..63
    const int k2c = (idx & 7) * 4;   // dword column 0..28 (= k/2)
    u32 v[4];
#pragma unroll
    for (int j = 0; j < 4; ++j) v[j] = Lt[(size_t)n * 33 + k2c + j];
    *(uint4*)(Wt + (size_t)(n0 + n) * KDIM + k0 + k2c * 2) = *(const uint4*)v;
  }
}

// ------- 256x256 GEMM: 4 waves, 128x128 per wave, ring-4, counted vmcnt ----
// LDS: ring of 4 slots per operand, slot = [256 rows][32 k] f16 (16 KB).
// Phase p reads slot p&3, stages piece p+3 into slot (p+3)&3 (last read at
// p-1; those ds_reads drained via lgkm0 before any wave passed p's barrier).
// Per wave per phase: 16 ds_read_b128 (af[8], bf[8]) + 64 MFMA. LDS:MFMA
// cycle ratio 768:1242 per CU (was 1152:1242 with 8 waves x 128x64).
// Stage: 4+4 global_load_lds per thread (8 vmcnt events); steady entry wait
// vmcnt(16) = stages p+1,p+2 outstanding. Never drains to 0 in the loop.
// Swizzle: physical chunk = logical ^ ((row>>1)&3), applied on the per-lane
// GLOBAL source (LDS dst linear) and on frag reads -> 0 bank conflicts.
__global__ __launch_bounds__(NT) void gemm_f16(const _Float16* __restrict__ A16,
                                               const _Float16* __restrict__ Wt,
                                               float* __restrict__ C) {
  __shared__ __align__(16) _Float16 As[4 * 256 * 32];  // 64 KB
  __shared__ __align__(16) _Float16 Bs[4 * 256 * 32];  // 64 KB

  const int tid = threadIdx.x;
  const int bx = blockIdx.x & 15;  // n-block
  const int by = blockIdx.x >> 4;  // m-block
  const int m_base = by * 256;
  const int n_base = bx * 256;

  const int wave = tid >> 6;
  const int lane = tid & 63;
  const int l15 = lane & 15;
  const int quad = lane >> 4;
  const int wm = (wave >> 1) * 128;  // wave m-band
  const int wn = (wave & 1) * 128;   // wave n-band
  const int gq = (l15 >> 1) & 3;     // row-swizzle term (row ≡ l15 mod 16)
  const int pchunk = quad ^ gq;      // physical 16B chunk for frag reads

  f32x4 acc[8][8];
#pragma unroll
  for (int i = 0; i < 8; ++i)
#pragma unroll
    for (int j = 0; j < 8; ++j) acc[i][j] = (f32x4)0.0f;

  // stage pieces (A khalf + B khalf) for phase p into slot p&3.
  // 4+4 global_load_lds per thread = 8 vmcnt events per wave per stage.
  auto stage = [&](int p) {
    const int T = p >> 1;        // K-tile
    const int h = p & 1;         // k-half within tile
    const int s = p & 3;         // slot
    const size_t kof = (size_t)T * 64 + (size_t)h * 32;
#pragma unroll
    for (int L = 0; L < 4; ++L) {
      const int cc = L * 256 + tid;        // 0..1023 : (row, phys chunk)
      const int row = cc >> 2;
      const int lch = (cc & 3) ^ ((row >> 1) & 3);  // logical chunk at phys
      load16_to_lds(A16 + (size_t)(m_base + row) * KDIM + kof + lch * 8,
                    (char*)As + (size_t)s * 16384 + (size_t)cc * 16);
    }
#pragma unroll
    for (int L = 0; L < 4; ++L) {
      const int cc = L * 256 + tid;
      const int row = cc >> 2;
      const int lch = (cc & 3) ^ ((row >> 1) & 3);
      load16_to_lds(Wt + (size_t)(n_base + row) * KDIM + kof + lch * 8,
                    (char*)Bs + (size_t)s * 16384 + (size_t)cc * 16);
    }
  };

  auto phase_body = [&](int p, bool dostage) {
    __builtin_amdgcn_s_barrier();
    asm volatile("" ::: "memory");  // no LDS access hoists above the barrier
    const int s = p & 3;
    const _Float16* Ab = (const _Float16*)((const char*)As + (size_t)s * 16384);
    const _Float16* Bb = (const _Float16*)((const char*)Bs + (size_t)s * 16384);
    f16x8 af[8], bf[8];
#pragma unroll
    for (int i = 0; i < 8; ++i) {
      const int row = wm + i * 16 + l15;
      af[i] = *(const f16x8*)(Ab + (size_t)row * 32 + pchunk * 8);
    }
#pragma unroll
    for (int j = 0; j < 8; ++j) {
      const int row = wn + j * 16 + l15;
      bf[j] = *(const f16x8*)(Bb + (size_t)row * 32 + pchunk * 8);
    }
    if (dostage) stage(p + 3);
    asm volatile("s_waitcnt lgkmcnt(0)" ::: "memory");
    __builtin_amdgcn_sched_barrier(0);  // keep MFMAs below the wait (rule 18)
    __builtin_amdgcn_s_setprio(1);
#pragma unroll
    for (int i = 0; i < 8; ++i)
#pragma unroll
      for (int j = 0; j < 8; ++j)
        acc[i][j] = __builtin_amdgcn_mfma_f32_16x16x32_f16(af[i], bf[j],
                                                           acc[i][j], 0, 0, 0);
    __builtin_amdgcn_s_setprio(0);
  };

  // prologue: pieces for phases 0,1,2 (24 vmcnt events in flight)
  stage(0);
  stage(1);
  stage(2);

  // 128 phases = 64 K-tiles x 2 k-halves. vmcnt(16): stages p+1,p+2 in
  // flight (8 events each); stage(p) guaranteed landed before the entry
  // barrier (all waves execute the wait pre-barrier).
  for (int p = 0; p < 125; ++p) {
    wait_vmcnt<16>();
    phase_body(p, true);
  }
  wait_vmcnt<16>();
  phase_body(125, false);
  wait_vmcnt<8>();
  phase_body(126, false);
  wait_vmcnt<0>();
  phase_body(127, false);

  // epilogue: C/D layout col=lane&15, row=quad*4+reg; fp16-round, store f32
#pragma unroll
  for (int i = 0; i < 8; ++i) {
#pragma unroll
    for (int j = 0; j < 8; ++j) {
      const int col = n_base + wn + j * 16 + l15;
#pragma unroll
      for (int r = 0; r < 4; ++r) {
        const int row = m_base + wm + i * 16 + quad * 4 + r;
        C[(size_t)row * NDIM + col] = __half2float(__float2half(acc[i][j][r]));
      }
    }
  }
}

// ---------------- fallback: fused single-kernel (round-3, 331 us) --------
#define STR 72
__global__ __launch_bounds__(NT) void qgemm_fused(
    const float* __restrict__ A, const int* __restrict__ Wq,
    const float* __restrict__ Sc, float* __restrict__ C) {
  __shared__ __align__(16) _Float16 As[128 * STR];
  __shared__ __align__(16) _Float16 Bs[128 * STR];
  const int tid = threadIdx.x;
  const int bx = blockIdx.x & 31, by = blockIdx.x >> 5;
  const int m_base = by * 128, n_base = bx * 128;
  const int wave = tid >> 6, lane = tid & 63;
  const int l15 = lane & 15, quad = lane >> 4;
  const int wm = (wave & 1) * 64, wn = (wave >> 1) * 64;
  const int bn_local = tid & 127, bk_half = (tid >> 7) * 8;
  const int gn = n_base + bn_local;
  f32x4 acc[4][4];
#pragma unroll
  for (int i = 0; i < 4; ++i)
#pragma unroll
    for (int j = 0; j < 4; ++j) acc[i][j] = (f32x4)0.0f;
  for (int kt = 0; kt < KDIM / 64; ++kt) {
    const int k0 = kt * 64;
    __syncthreads();
#pragma unroll
    for (int i = 0; i < 8; ++i) {
      const int c = i * 256 + tid;
      const int row = c >> 4, col4 = (c & 15) * 4;
      const float4 f = *(const float4*)(A + (size_t)(m_base + row) * KDIM + k0 + col4);
      u32 pk[2];
      pk[0] = pkrtz(f.x, f.y);
      pk[1] = pkrtz(f.z, f.w);
      *(uint2*)&As[(size_t)row * STR + col4] = *(const uint2*)pk;
    }
    {
      const __half hs = __float2half(Sc[(size_t)(k0 >> 7) * NDIM + gn]);
      const __half2 s2 = __half2half2(hs);
      const __half2 nb2 = __half2half2(__hmul(hs, __float2half(-1024.0f)));
#pragma unroll
      for (int it = 0; it < 4; ++it) {
        const int k = bk_half + it * 16;
        u32 v[8];
#pragma unroll
        for (int j = 0; j < 8; ++j)
          v[j] = (u32)Wq[(size_t)(k0 + k + j) * NDIM + gn];
        u32 pk[4];
#pragma unroll
        for (int p = 0; p < 4; ++p) {
          u32 u = v[2 * p] | (v[2 * p + 1] << 16) | 0x64006400u;
          pk[p] = as_u32(__hfma2(as_half2(u), s2, nb2));
        }
        *(uint4*)&Bs[(size_t)bn_local * STR + k] = *(const uint4*)pk;
      }
    }
    __syncthreads();
#pragma unroll
    for (int ks = 0; ks < 64; ks += 32) {
      f16x8 af[4], bf[4];
#pragma unroll
      for (int i = 0; i < 4; ++i)
        af[i] = *(const f16x8*)&As[(size_t)(wm + i * 16 + l15) * STR + ks + quad * 8];
#pragma unroll
      for (int j = 0; j < 4; ++j)
        bf[j] = *(const f16x8*)&Bs[(size_t)(wn + j * 16 + l15) * STR + ks + quad * 8];
#pragma unroll
      for (int i = 0; i < 4; ++i)
#pragma unroll
        for (int j = 0; j < 4; ++j)
          acc[i][j] = __builtin_amdgcn_mfma_f32_16x16x32_f16(af[i], bf[j],
                                                             acc[i][j], 0, 0, 0);
    }
  }
#pragma unroll
  for (int i = 0; i < 4; ++i)
#pragma unroll
    for (int j = 0; j < 4; ++j) {
      const int col = n_base + wn + j * 16 + l15;
#pragma unroll
      for (int r = 0; r < 4; ++r) {
        const int row = m_base + wm + i * 16 + quad * 4 + r;
        C[(size_t)row * NDIM + col] = __half2float(__float2half(acc[i][j][r]));
      }
    }
}

extern "C" void kernel_launch(void* const* d_in, const int* in_sizes, int n_in,
                              void* d_out, int out_size, void* d_ws, size_t ws_size,
                              hipStream_t stream) {
  const float* a = (const float*)d_in[0];
  const int* wq = (const int*)d_in[1];
  const float* sc = (const float*)d_in[2];
  float* out = (float*)d_out;

  const size_t a16_bytes = (size_t)MDIM * KDIM * 2;  // 32 MiB
  const size_t wt_bytes = (size_t)NDIM * KDIM * 2;   // 32 MiB

  if (ws_size >= a16_bytes + wt_bytes) {
    _Float16* a16 = (_Float16*)d_ws;
    _Float16* wt = (_Float16*)((char*)d_ws + a16_bytes);
    const int a_blocks = (MDIM * KDIM) / (NT * 8);  // 8192
    prep<<<WBLK + a_blocks, NT, 0, stream>>>(a, a16, wq, sc, wt);
    gemm_f16<<<(MDIM / 256) * (NDIM / 256), NT, 0, stream>>>(a16, wt, out);
  } else {
    qgemm_fused<<<(MDIM / 128) * (NDIM / 128), NT, 0, stream>>>(a, wq, sc, out);
  }
}